// Round 6
// baseline (164.118 us; speedup 1.0000x reference)
//
#include <hip/hip_runtime.h>
#include <math.h>

#define BATCH 8
#define CIN   512
#define DQKV  768
#define NHEAD 8
#define HW    1024

typedef __attribute__((ext_vector_type(8))) short  short8;
typedef __attribute__((ext_vector_type(4))) float  float4v;

__device__ __forceinline__ ushort f2bf(float f) {
    union { float f; unsigned u; } c; c.f = f;
    unsigned u = c.u + 0x7fffu + ((c.u >> 16) & 1u);   // RNE
    return (ushort)(u >> 16);
}

__device__ __forceinline__ void async_ld16(const ushort* g, ushort* l) {
    auto gp = (const __attribute__((address_space(1))) unsigned int*)g;
    auto lp = (__attribute__((address_space(3))) unsigned int*)l;
    __builtin_amdgcn_global_load_lds(gp, lp, 16, 0, 0);
}

// ---------------------------------------------------------------------------
// Transpose + fp32->bf16: per batch, in [K][N] fp32 -> out [N][K] bf16.
// ---------------------------------------------------------------------------
__global__ __launch_bounds__(256)
void transpose_cvt(const float* __restrict__ in, ushort* __restrict__ out,
                   int K, int N)
{
    __shared__ float Ts[64][65];
    const int b  = blockIdx.z;
    const int k0 = blockIdx.y * 64;
    const int n0 = blockIdx.x * 64;
    const int t  = threadIdx.x;
    const float* ib = in + (size_t)b * K * N;
    ushort*      ob = out + (size_t)b * N * K;

    const int r  = t >> 4;
    const int c4 = (t & 15) * 4;
    #pragma unroll
    for (int p = 0; p < 4; ++p) {
        float4 v = *(const float4*)(ib + (size_t)(k0 + r + 16 * p) * N + n0 + c4);
        Ts[r + 16 * p][c4 + 0] = v.x;
        Ts[r + 16 * p][c4 + 1] = v.y;
        Ts[r + 16 * p][c4 + 2] = v.z;
        Ts[r + 16 * p][c4 + 3] = v.w;
    }
    __syncthreads();

    const int nl = t >> 3;
    const int kc = (t & 7) * 8;
    #pragma unroll
    for (int p = 0; p < 2; ++p) {
        int n = nl + 32 * p;
        uint4 u;
        u.x = (uint)f2bf(Ts[kc + 0][n]) | ((uint)f2bf(Ts[kc + 1][n]) << 16);
        u.y = (uint)f2bf(Ts[kc + 2][n]) | ((uint)f2bf(Ts[kc + 3][n]) << 16);
        u.z = (uint)f2bf(Ts[kc + 4][n]) | ((uint)f2bf(Ts[kc + 5][n]) << 16);
        u.w = (uint)f2bf(Ts[kc + 6][n]) | ((uint)f2bf(Ts[kc + 7][n]) << 16);
        *(uint4*)(ob + (size_t)(n0 + n) * K + k0 + kc) = u;
    }
}

// elementwise fp32 -> bf16 (weights), 8 elems/thread
__global__ void cvt_bf16(const float* __restrict__ in, ushort* __restrict__ out, int n8)
{
    int i = blockIdx.x * blockDim.x + threadIdx.x;
    if (i >= n8) return;
    const float4* p = (const float4*)(in + (size_t)i * 8);
    float4 a = p[0], b = p[1];
    uint4 u;
    u.x = (uint)f2bf(a.x) | ((uint)f2bf(a.y) << 16);
    u.y = (uint)f2bf(a.z) | ((uint)f2bf(a.w) << 16);
    u.z = (uint)f2bf(b.x) | ((uint)f2bf(b.y) << 16);
    u.w = (uint)f2bf(b.z) | ((uint)f2bf(b.w) << 16);
    *(uint4*)(out + (size_t)i * 8) = u;
}

// ---------------------------------------------------------------------------
// qk_transform: qkv_b[b][ch][sp] bf16 (ch 0..511 = Q,K) ->
//   Qt/Kt[b][n][sp][32d] bf16 (spatial-major per head). Unchanged.
// ---------------------------------------------------------------------------
__global__ __launch_bounds__(256)
void qk_transform(const ushort* __restrict__ qkv, ushort* __restrict__ Qt,
                  ushort* __restrict__ Kt)
{
    __shared__ ushort Ts[32 * 264];
    const int b   = blockIdx.z;
    const int g   = blockIdx.y;
    const int sp0 = blockIdx.x * 256;
    const int t   = threadIdx.x;

    const ushort* src = qkv + ((size_t)b * DQKV + g * 32) * HW;
    ushort* dst = (g < 8 ? Qt : Kt) + ((size_t)b * NHEAD + (g & 7)) * (HW * 32);

    #pragma unroll
    for (int p = 0; p < 4; ++p) {
        int d = (t >> 5) + p * 8;
        int c = t & 31;
        uint4 u = *(const uint4*)(src + (size_t)d * HW + sp0 + c * 8);
        *(uint4*)&Ts[d * 264 + c * 8] = u;
    }
    __syncthreads();

    ushort* orow = dst + (size_t)(sp0 + t) * 32;
    #pragma unroll
    for (int c = 0; c < 4; ++c) {
        ushort v[8];
        #pragma unroll
        for (int j = 0; j < 8; ++j) v[j] = Ts[(c * 8 + j) * 264 + t];
        *(uint4*)(orow + c * 8) = *(uint4*)v;
    }
}

// ---------------------------------------------------------------------------
// bf16 MFMA GEMM (m97 structure), unchanged.
// ---------------------------------------------------------------------------
template<int M, int K, bool QSCALE, bool OUTBF>
__global__ __launch_bounds__(256, 2)
void gemm_bt(const ushort* __restrict__ A, const ushort* __restrict__ Bt,
             const float* __restrict__ bias, void* __restrict__ Oo)
{
    __shared__ __align__(16) ushort As[128 * 64];
    __shared__ __align__(16) ushort Bs[128 * 64];

    const int b    = blockIdx.z;
    const int m0   = blockIdx.y * 128;
    const int n0   = blockIdx.x * 128;
    const int t    = threadIdx.x;
    const int lane = t & 63;
    const int wave = t >> 6;
    const int l16  = lane & 15;
    const int quad = lane >> 4;
    const int wm   = (wave & 1) * 64;
    const int wn   = (wave >> 1) * 64;

    const ushort* Bb = Bt + (size_t)b * HW * K;

    float4v acc[4][4];
    #pragma unroll
    for (int i = 0; i < 4; ++i)
        #pragma unroll
        for (int j = 0; j < 4; ++j)
            acc[i][j] = (float4v){0.f, 0.f, 0.f, 0.f};

    const int srow = t >> 3;
    const int sg   = t & 7;

    for (int k0 = 0; k0 < K; k0 += 64) {
        __syncthreads();
        #pragma unroll
        for (int is = 0; is < 4; ++is) {
            int row = srow + is * 32;
            int gch = sg ^ (row & 7);
            async_ld16(A  + (size_t)(m0 + row) * K + k0 + gch * 8,
                       As + (size_t)t * 8 + is * 2048);
            async_ld16(Bb + (size_t)(n0 + row) * K + k0 + gch * 8,
                       Bs + (size_t)t * 8 + is * 2048);
        }
        __syncthreads();

        #pragma unroll
        for (int ks = 0; ks < 2; ++ks) {
            short8 af[4], bf[4];
            #pragma unroll
            for (int i = 0; i < 4; ++i) {
                int row = wm + i * 16 + l16;
                int ch  = (ks * 4 + quad) ^ (row & 7);
                af[i] = *(const short8*)&As[row * 64 + ch * 8];
            }
            #pragma unroll
            for (int j = 0; j < 4; ++j) {
                int row = wn + j * 16 + l16;
                int ch  = (ks * 4 + quad) ^ (row & 7);
                bf[j] = *(const short8*)&Bs[row * 64 + ch * 8];
            }
            #pragma unroll
            for (int i = 0; i < 4; ++i)
                #pragma unroll
                for (int j = 0; j < 4; ++j)
                    acc[i][j] = __builtin_amdgcn_mfma_f32_16x16x32_bf16(
                        af[i], bf[j], acc[i][j], 0, 0, 0);
        }
    }

    #pragma unroll
    for (int i = 0; i < 4; ++i) {
        #pragma unroll
        for (int rr = 0; rr < 4; ++rr) {
            int m = m0 + wm + i * 16 + quad * 4 + rr;
            float bi = bias[m];
            float sc = QSCALE ? ((m < 256) ? 0.17677669529663687f : 1.0f) : 1.0f;
            #pragma unroll
            for (int j = 0; j < 4; ++j) {
                int n = n0 + wn + j * 16 + l16;
                float val = (acc[i][j][rr] + bi) * sc;
                if (OUTBF)
                    ((ushort*)Oo)[((size_t)b * M + m) * HW + n] = f2bf(val);
                else
                    ((float*)Oo)[((size_t)b * M + m) * HW + n] = val;
            }
        }
    }
}

// ---------------------------------------------------------------------------
// MFMA attention core v5 — strided-q blocks for coalesced epilogue.
// Block = (b, j, uh): q-set = { (uh*16+ui)*32 + j : ui in 0..15 }  (16 q's).
// 512 thr (8 waves), k-tile 128, 8 iters, 2 barriers/iter.
// Logits: wave w = 16-k chunk, all 8 heads in registers (S[8] = 32 VGPRs);
// head-axis softmax pure register math. Ws LDS (34.8 KB) only for C->A
// layout change. PV: wave = head; V B-frags direct from global.
// Epilogue: stage O to LDS, write ab as 16B stores in 32B channel runs
// (sibling uh-block fills the other 32B of each 64B line).
// ---------------------------------------------------------------------------
#define WROW 136   // Ws row stride (shorts): 128 data + 8 pad, 16B-aligned rows
#define OROW 132   // Ot row stride (shorts)

__global__ __launch_bounds__(512, 4)
void attn_kernel(const ushort* __restrict__ qkv, const ushort* __restrict__ Qt,
                 const ushort* __restrict__ Kt, ushort* __restrict__ ab)
{
    __shared__ __align__(16) ushort Ws[NHEAD * 16 * WROW];   // 34816 B

    const int t    = threadIdx.x;
    const int b    = blockIdx.y;
    const int j    = blockIdx.x >> 1;      // hw-row group (q & 31)
    const int uh   = blockIdx.x & 1;       // u half (q >> 5 in [uh*16, uh*16+16))
    const int wave = t >> 6;               // logits: k-chunk; PV: head
    const int lane = t & 63;
    const int l16  = lane & 15;
    const int quad = lane >> 4;

    const ushort* Vb  = qkv + ((size_t)b * DQKV + 512) * HW;
    const ushort* Qtb = Qt + (size_t)b * (NHEAD * HW * 32);
    const ushort* Ktb = Kt + (size_t)b * (NHEAD * HW * 32);

    // ---- preload Q B-frags (loop-invariant): lane l16 = ui -> q = (uh*16+ui)*32 + j
    const int qlane = (uh * 16 + l16) * 32 + j;
    short8 qf[NHEAD];
    #pragma unroll
    for (int h = 0; h < NHEAD; ++h)
        qf[h] = *(const short8*)(Qtb + ((size_t)h * HW + qlane) * 32 + quad * 8);

    float4v oacc[2];                       // [dsub], head = wave, q rows = quad*4+r
    oacc[0] = (float4v){0.f, 0.f, 0.f, 0.f};
    oacc[1] = (float4v){0.f, 0.f, 0.f, 0.f};

    for (int k0 = 0; k0 < HW; k0 += 128) {
        // ---- logits: S^T[k][ui] for all 8 heads; wave's 16-k chunk ----
        const int kk = k0 + wave * 16 + l16;
        float4v S[NHEAD];
        #pragma unroll
        for (int h = 0; h < NHEAD; ++h) {
            short8 kf = *(const short8*)(Ktb + ((size_t)h * HW + kk) * 32 + quad * 8);
            S[h] = __builtin_amdgcn_mfma_f32_16x16x32_bf16(
                kf, qf[h], (float4v){0.f, 0.f, 0.f, 0.f}, 0, 0, 0);
        }

        // ---- head-axis softmax in registers ----
        float4v mx = S[0];
        #pragma unroll
        for (int h = 1; h < NHEAD; ++h)
            #pragma unroll
            for (int r = 0; r < 4; ++r) mx[r] = fmaxf(mx[r], S[h][r]);
        float4v sum = (float4v){0.f, 0.f, 0.f, 0.f};
        #pragma unroll
        for (int h = 0; h < NHEAD; ++h)
            #pragma unroll
            for (int r = 0; r < 4; ++r) {
                S[h][r] = __expf(S[h][r] - mx[r]);
                sum[r] += S[h][r];
            }
        float4v inv;
        #pragma unroll
        for (int r = 0; r < 4; ++r) inv[r] = __builtin_amdgcn_rcpf(sum[r]);
        uint2 wpk[NHEAD];
        #pragma unroll
        for (int h = 0; h < NHEAD; ++h) {
            wpk[h].x = (uint)f2bf(S[h][0] * inv[0]) | ((uint)f2bf(S[h][1] * inv[1]) << 16);
            wpk[h].y = (uint)f2bf(S[h][2] * inv[2]) | ((uint)f2bf(S[h][3] * inv[3]) << 16);
        }

        __syncthreads();   // prev iter's PV done reading Ws

        // ---- W writes: Ws[h][ui = l16][k = wave*16 + quad*4 + 0..3] ----
        #pragma unroll
        for (int h = 0; h < NHEAD; ++h)
            *(uint2*)&Ws[(size_t)(h * 16 + l16) * WROW + wave * 16 + quad * 4] = wpk[h];

        __syncthreads();   // Ws ready

        // ---- PV: head = wave; O[ui][d] += W[ui][k] V[d][k] ----
        #pragma unroll
        for (int ks = 0; ks < 4; ++ks) {
            short8 wf = *(const short8*)&Ws[(size_t)(wave * 16 + l16) * WROW + ks * 32 + quad * 8];
            #pragma unroll
            for (int ds = 0; ds < 2; ++ds) {
                short8 vf = *(const short8*)(Vb + (size_t)(wave * 32 + ds * 16 + l16) * HW
                                             + k0 + ks * 32 + quad * 8);
                oacc[ds] = __builtin_amdgcn_mfma_f32_16x16x32_bf16(wf, vf, oacc[ds], 0, 0, 0);
            }
        }
    }

    // ---- epilogue: stage O in LDS [d][c_local], then coalesced ab writes ----
    __syncthreads();                        // all PV reads of Ws done
    ushort* Ot = Ws;                        // reuse (32 * OROW shorts = 8448 B)
    #pragma unroll
    for (int ds = 0; ds < 2; ++ds) {
        int d = ds * 16 + l16;
        #pragma unroll
        for (int r = 0; r < 4; ++r)
            Ot[(size_t)d * OROW + wave * 16 + quad * 4 + r] = f2bf(oacc[ds][r]);
    }
    __syncthreads();

    // thread t: d = t>>4, c8 = (t&15)*8; global c = h*32 + uh*16 + (c8&15)
    {
        int d  = t >> 4;
        int c8 = (t & 15) * 8;
        uint2 a = *(const uint2*)&Ot[(size_t)d * OROW + c8];
        uint2 b2 = *(const uint2*)&Ot[(size_t)d * OROW + c8 + 4];
        int h   = c8 >> 4;
        int col = h * 32 + uh * 16 + (c8 & 15);
        uint4 u = make_uint4(a.x, a.y, b2.x, b2.y);
        *(uint4*)(ab + ((size_t)b * HW + j * 32 + d) * 256 + col) = u;
    }
}

// ---------------------------------------------------------------------------
extern "C" void kernel_launch(void* const* d_in, const int* in_sizes, int n_in,
                              void* d_out, int out_size, void* d_ws, size_t ws_size,
                              hipStream_t stream)
{
    const float* x      = (const float*)d_in[0];
    const float* w_qkv  = (const float*)d_in[1];
    const float* b_qkv  = (const float*)d_in[2];
    const float* w_attn = (const float*)d_in[3];
    const float* b_attn = (const float*)d_in[4];
    float* out = (float*)d_out;

    // workspace (26.2 MB): qkv_b | xb (aliased by Qt+Kt after gemm1) | ab | wb1 | wb2
    ushort* qkv_b = (ushort*)d_ws;                 // 6291456 sh
    ushort* xb    = qkv_b + 6291456;               // 4194304 sh
    ushort* Qt    = xb;                            // alias: 2097152 sh
    ushort* Kt    = xb + 2097152;                  // alias: 2097152 sh
    ushort* ab    = xb + 4194304;                  // 2097152 sh
    ushort* wb1   = ab + 2097152;                  // 393216 sh
    ushort* wb2   = wb1 + 393216;                  // 131072 sh

    cvt_bf16<<<192, 256, 0, stream>>>(w_qkv, wb1, 49152);
    cvt_bf16<<<64, 256, 0, stream>>>(w_attn, wb2, 16384);
    transpose_cvt<<<dim3(16, 8, BATCH), 256, 0, stream>>>(x, xb, CIN, HW);

    gemm_bt<DQKV, CIN, true, true>
        <<<dim3(8, 6, BATCH), 256, 0, stream>>>(wb1, xb, b_qkv, qkv_b);

    qk_transform<<<dim3(4, 16, BATCH), 256, 0, stream>>>(qkv_b, Qt, Kt);

    attn_kernel<<<dim3(64, BATCH), 512, 0, stream>>>(qkv_b, Qt, Kt, ab);

    gemm_bt<512, 256, false, false>
        <<<dim3(8, 4, BATCH), 256, 0, stream>>>(wb2, ab, b_attn, out);
}

// Round 7
// 156.736 us; speedup vs baseline: 1.0471x; 1.0471x over previous
//
#include <hip/hip_runtime.h>
#include <hip/hip_bf16.h>
#include <math.h>

#define BATCH 8
#define CIN   512
#define DQKV  768
#define NHEAD 8
#define HW    1024

typedef __attribute__((ext_vector_type(8))) short  short8;
typedef __attribute__((ext_vector_type(4))) float  float4v;

__device__ __forceinline__ ushort f2bf(float f) {
    union { float f; unsigned u; } c; c.f = f;
    unsigned u = c.u + 0x7fffu + ((c.u >> 16) & 1u);   // RNE
    return (ushort)(u >> 16);
}

// packed 2x fp32 -> bf16 (RNE), low = a
__device__ __forceinline__ uint pkbf(float a, float b) {
    union { __hip_bfloat162 h; uint u; } c;
    c.h = __float22bfloat162_rn(make_float2(a, b));
    return c.u;
}

__device__ __forceinline__ void async_ld16(const ushort* g, ushort* l) {
    auto gp = (const __attribute__((address_space(1))) unsigned int*)g;
    auto lp = (__attribute__((address_space(3))) unsigned int*)l;
    __builtin_amdgcn_global_load_lds(gp, lp, 16, 0, 0);
}

// ---------------------------------------------------------------------------
// Transpose + fp32->bf16: per batch, in [K][N] fp32 -> out [N][K] bf16.
// ---------------------------------------------------------------------------
__global__ __launch_bounds__(256)
void transpose_cvt(const float* __restrict__ in, ushort* __restrict__ out,
                   int K, int N)
{
    __shared__ float Ts[64][65];
    const int b  = blockIdx.z;
    const int k0 = blockIdx.y * 64;
    const int n0 = blockIdx.x * 64;
    const int t  = threadIdx.x;
    const float* ib = in + (size_t)b * K * N;
    ushort*      ob = out + (size_t)b * N * K;

    const int r  = t >> 4;
    const int c4 = (t & 15) * 4;
    #pragma unroll
    for (int p = 0; p < 4; ++p) {
        float4 v = *(const float4*)(ib + (size_t)(k0 + r + 16 * p) * N + n0 + c4);
        Ts[r + 16 * p][c4 + 0] = v.x;
        Ts[r + 16 * p][c4 + 1] = v.y;
        Ts[r + 16 * p][c4 + 2] = v.z;
        Ts[r + 16 * p][c4 + 3] = v.w;
    }
    __syncthreads();

    const int nl = t >> 3;
    const int kc = (t & 7) * 8;
    #pragma unroll
    for (int p = 0; p < 2; ++p) {
        int n = nl + 32 * p;
        uint4 u;
        u.x = pkbf(Ts[kc + 0][n], Ts[kc + 1][n]);
        u.y = pkbf(Ts[kc + 2][n], Ts[kc + 3][n]);
        u.z = pkbf(Ts[kc + 4][n], Ts[kc + 5][n]);
        u.w = pkbf(Ts[kc + 6][n], Ts[kc + 7][n]);
        *(uint4*)(ob + (size_t)(n0 + n) * K + k0 + kc) = u;
    }
}

// elementwise fp32 -> bf16 (weights), 8 elems/thread
__global__ void cvt_bf16(const float* __restrict__ in, ushort* __restrict__ out, int n8)
{
    int i = blockIdx.x * blockDim.x + threadIdx.x;
    if (i >= n8) return;
    const float4* p = (const float4*)(in + (size_t)i * 8);
    float4 a = p[0], b = p[1];
    uint4 u;
    u.x = pkbf(a.x, a.y);
    u.y = pkbf(a.z, a.w);
    u.z = pkbf(b.x, b.y);
    u.w = pkbf(b.z, b.w);
    *(uint4*)(out + (size_t)i * 8) = u;
}

// ---------------------------------------------------------------------------
// bf16 MFMA GEMM (m97 structure).
// OUTMODE 0: fp32 natural O[b][m][n].
// OUTMODE 2: qkv split — m0<512: transposed bf16 into Qt/Kt[b][head][sp][32d]
//            (LDS-staged, coalesced); m0>=512: bf16 natural into vb[b][m-512][n].
// ---------------------------------------------------------------------------
#define TEW 136    // epilogue transpose tile row stride (shorts)

template<int M, int K, bool QSCALE, int OUTMODE>
__global__ __launch_bounds__(256, 2)
void gemm_bt(const ushort* __restrict__ A, const ushort* __restrict__ Bt,
             const float* __restrict__ bias, void* __restrict__ Oo,
             ushort* __restrict__ qt, ushort* __restrict__ kt)
{
    __shared__ __align__(16) ushort SH[16384];
    ushort* As = SH;
    ushort* Bs = SH + 8192;

    const int b    = blockIdx.z;
    const int m0   = blockIdx.y * 128;
    const int n0   = blockIdx.x * 128;
    const int t    = threadIdx.x;
    const int lane = t & 63;
    const int wave = t >> 6;
    const int l16  = lane & 15;
    const int quad = lane >> 4;
    const int wm   = (wave & 1) * 64;
    const int wn   = (wave >> 1) * 64;

    const ushort* Bb = Bt + (size_t)b * HW * K;

    float4v acc[4][4];
    #pragma unroll
    for (int i = 0; i < 4; ++i)
        #pragma unroll
        for (int j = 0; j < 4; ++j)
            acc[i][j] = (float4v){0.f, 0.f, 0.f, 0.f};

    const int srow = t >> 3;
    const int sg   = t & 7;

    for (int k0 = 0; k0 < K; k0 += 64) {
        __syncthreads();
        #pragma unroll
        for (int is = 0; is < 4; ++is) {
            int row = srow + is * 32;
            int gch = sg ^ (row & 7);
            async_ld16(A  + (size_t)(m0 + row) * K + k0 + gch * 8,
                       As + (size_t)t * 8 + is * 2048);
            async_ld16(Bb + (size_t)(n0 + row) * K + k0 + gch * 8,
                       Bs + (size_t)t * 8 + is * 2048);
        }
        __syncthreads();

        #pragma unroll
        for (int ks = 0; ks < 2; ++ks) {
            short8 af[4], bf[4];
            #pragma unroll
            for (int i = 0; i < 4; ++i) {
                int row = wm + i * 16 + l16;
                int ch  = (ks * 4 + quad) ^ (row & 7);
                af[i] = *(const short8*)&As[row * 64 + ch * 8];
            }
            #pragma unroll
            for (int j = 0; j < 4; ++j) {
                int row = wn + j * 16 + l16;
                int ch  = (ks * 4 + quad) ^ (row & 7);
                bf[j] = *(const short8*)&Bs[row * 64 + ch * 8];
            }
            #pragma unroll
            for (int i = 0; i < 4; ++i)
                #pragma unroll
                for (int j = 0; j < 4; ++j)
                    acc[i][j] = __builtin_amdgcn_mfma_f32_16x16x32_bf16(
                        af[i], bf[j], acc[i][j], 0, 0, 0);
        }
    }

    if (OUTMODE == 2 && m0 < 512) {
        // ---- transposed epilogue -> Qt/Kt[b][head][sp][32d] ----
        ushort* dst = (m0 < 256) ? qt : kt;
        const int headbase = (m0 & 255) >> 5;                 // 0 or 4
        const float sc = (QSCALE && m0 < 256) ? 0.17677669529663687f : 1.0f;
        #pragma unroll
        for (int hn = 0; hn < 2; ++hn) {
            __syncthreads();
            if ((wave >> 1) == hn) {
                #pragma unroll
                for (int i = 0; i < 4; ++i) {
                    int m_l = wm + i * 16 + quad * 4;
                    float bi[4];
                    #pragma unroll
                    for (int rr = 0; rr < 4; ++rr) bi[rr] = bias[m0 + m_l + rr];
                    #pragma unroll
                    for (int j = 0; j < 4; ++j) {
                        int n_l = j * 16 + l16;               // 0..63 within half
                        uint2 pk;
                        pk.x = pkbf((acc[i][j][0] + bi[0]) * sc,
                                    (acc[i][j][1] + bi[1]) * sc);
                        pk.y = pkbf((acc[i][j][2] + bi[2]) * sc,
                                    (acc[i][j][3] + bi[3]) * sc);
                        *(uint2*)&SH[n_l * TEW + m_l] = pk;
                    }
                }
            }
            __syncthreads();
            #pragma unroll
            for (int p = 0; p < 4; ++p) {
                int idx = p * 256 + t;
                int d8 = idx & 3, h_l = (idx >> 2) & 3, n_l = idx >> 4;
                uint4 u = *(const uint4*)&SH[n_l * TEW + h_l * 32 + d8 * 8];
                size_t a = ((size_t)(b * NHEAD + headbase + h_l) * HW
                            + (n0 + hn * 64 + n_l)) * 32 + d8 * 8;
                *(uint4*)(dst + a) = u;
            }
        }
    } else {
        #pragma unroll
        for (int i = 0; i < 4; ++i) {
            #pragma unroll
            for (int rr = 0; rr < 4; ++rr) {
                int m = m0 + wm + i * 16 + quad * 4 + rr;
                float bi = bias[m];
                #pragma unroll
                for (int j = 0; j < 4; ++j) {
                    int n = n0 + wn + j * 16 + l16;
                    float val = acc[i][j][rr] + bi;
                    if (OUTMODE == 2)
                        ((ushort*)Oo)[((size_t)b * 256 + (m & 255)) * HW + n] = f2bf(val);
                    else
                        ((float*)Oo)[((size_t)b * M + m) * HW + n] = val;
                }
            }
        }
    }
}

// ---------------------------------------------------------------------------
// MFMA attention core v6 — software-pipelined register softmax.
// Block = (b, j, uh): q-set = { (uh*16+ui)*32 + j : ui in 0..15 }.
// 512 thr (8 waves), k-tile 128, 8 iters.
// Pipeline: softmax for tile i+1 (registers, no LDS) is computed in the SAME
// unsynchronized stretch as PV for tile i -> K-loads, V-loads, 16 MFMAs and
// the softmax VALU chain all interleave; barriers only guard the W write.
// ---------------------------------------------------------------------------
#define WROW 136   // Ws row stride (shorts)
#define OROW 132   // Ot row stride (shorts)

__global__ __launch_bounds__(512, 4)
void attn_kernel(const ushort* __restrict__ vb, const ushort* __restrict__ Qt,
                 const ushort* __restrict__ Kt, ushort* __restrict__ ab)
{
    __shared__ __align__(16) ushort Ws[NHEAD * 16 * WROW];   // 34816 B

    const int t    = threadIdx.x;
    const int b    = blockIdx.y;
    const int j    = blockIdx.x >> 1;      // hw-row group (q & 31)
    const int uh   = blockIdx.x & 1;       // u half
    const int wave = t >> 6;               // logits: k-chunk; PV: head
    const int lane = t & 63;
    const int l16  = lane & 15;
    const int quad = lane >> 4;

    const ushort* Vb  = vb + (size_t)b * 256 * HW;
    const ushort* Qtb = Qt + (size_t)b * (NHEAD * HW * 32);
    const ushort* Ktb = Kt + (size_t)b * (NHEAD * HW * 32);

    // ---- preload Q B-frags: lane l16 = ui -> q = (uh*16+ui)*32 + j ----
    const int qlane = (uh * 16 + l16) * 32 + j;
    short8 qf[NHEAD];
    #pragma unroll
    for (int h = 0; h < NHEAD; ++h)
        qf[h] = *(const short8*)(Qtb + ((size_t)h * HW + qlane) * 32 + quad * 8);

    // logits tile -> softmax -> packed bf16 weights (pure registers)
    auto compute_wpk = [&](int k0, uint2* wpk) {
        const int kk = k0 + wave * 16 + l16;
        float4v S[NHEAD];
        #pragma unroll
        for (int h = 0; h < NHEAD; ++h) {
            short8 kf = *(const short8*)(Ktb + ((size_t)h * HW + kk) * 32 + quad * 8);
            S[h] = __builtin_amdgcn_mfma_f32_16x16x32_bf16(
                kf, qf[h], (float4v){0.f, 0.f, 0.f, 0.f}, 0, 0, 0);
        }
        float4v mx = S[0];
        #pragma unroll
        for (int h = 1; h < NHEAD; ++h)
            #pragma unroll
            for (int r = 0; r < 4; ++r) mx[r] = fmaxf(mx[r], S[h][r]);
        float4v sum = (float4v){0.f, 0.f, 0.f, 0.f};
        #pragma unroll
        for (int h = 0; h < NHEAD; ++h)
            #pragma unroll
            for (int r = 0; r < 4; ++r) {
                S[h][r] = __expf(S[h][r] - mx[r]);
                sum[r] += S[h][r];
            }
        float4v inv;
        #pragma unroll
        for (int r = 0; r < 4; ++r) inv[r] = __builtin_amdgcn_rcpf(sum[r]);
        #pragma unroll
        for (int h = 0; h < NHEAD; ++h) {
            wpk[h].x = pkbf(S[h][0] * inv[0], S[h][1] * inv[1]);
            wpk[h].y = pkbf(S[h][2] * inv[2], S[h][3] * inv[3]);
        }
    };

    float4v oacc[2];
    oacc[0] = (float4v){0.f, 0.f, 0.f, 0.f};
    oacc[1] = (float4v){0.f, 0.f, 0.f, 0.f};

    // prologue: weights for tile 0
    {
        uint2 w0[NHEAD];
        compute_wpk(0, w0);
        #pragma unroll
        for (int h = 0; h < NHEAD; ++h)
            *(uint2*)&Ws[(size_t)(h * 16 + l16) * WROW + wave * 16 + quad * 4] = w0[h];
    }
    __syncthreads();

    for (int i = 0; i < 8; ++i) {
        const int k0 = i * 128;

        uint2 nxt[NHEAD];
        if (i < 7) compute_wpk(k0 + 128, nxt);   // independent of PV below

        // ---- PV on tile i: head = wave; O[ui][d] += W[ui][k] V[d][k] ----
        #pragma unroll
        for (int ks = 0; ks < 4; ++ks) {
            short8 wf = *(const short8*)&Ws[(size_t)(wave * 16 + l16) * WROW + ks * 32 + quad * 8];
            #pragma unroll
            for (int ds = 0; ds < 2; ++ds) {
                short8 vf = *(const short8*)(Vb + (size_t)(wave * 32 + ds * 16 + l16) * HW
                                             + k0 + ks * 32 + quad * 8);
                oacc[ds] = __builtin_amdgcn_mfma_f32_16x16x32_bf16(wf, vf, oacc[ds], 0, 0, 0);
            }
        }

        if (i < 7) {
            __syncthreads();   // PV done reading Ws
            #pragma unroll
            for (int h = 0; h < NHEAD; ++h)
                *(uint2*)&Ws[(size_t)(h * 16 + l16) * WROW + wave * 16 + quad * 4] = nxt[h];
            __syncthreads();   // Ws ready
        }
    }

    // ---- epilogue: stage O in LDS [d][c_local], then coalesced ab writes ----
    __syncthreads();
    ushort* Ot = Ws;
    #pragma unroll
    for (int ds = 0; ds < 2; ++ds) {
        int d = ds * 16 + l16;
        #pragma unroll
        for (int r = 0; r < 4; ++r)
            Ot[(size_t)d * OROW + wave * 16 + quad * 4 + r] = f2bf(oacc[ds][r]);
    }
    __syncthreads();

    {
        int d  = t >> 4;
        int c8 = (t & 15) * 8;
        uint2 a = *(const uint2*)&Ot[(size_t)d * OROW + c8];
        uint2 b2 = *(const uint2*)&Ot[(size_t)d * OROW + c8 + 4];
        int h   = c8 >> 4;
        int col = h * 32 + uh * 16 + (c8 & 15);
        uint4 u = make_uint4(a.x, a.y, b2.x, b2.y);
        *(uint4*)(ab + ((size_t)b * HW + j * 32 + d) * 256 + col) = u;
    }
}

// ---------------------------------------------------------------------------
extern "C" void kernel_launch(void* const* d_in, const int* in_sizes, int n_in,
                              void* d_out, int out_size, void* d_ws, size_t ws_size,
                              hipStream_t stream)
{
    const float* x      = (const float*)d_in[0];
    const float* w_qkv  = (const float*)d_in[1];
    const float* b_qkv  = (const float*)d_in[2];
    const float* w_attn = (const float*)d_in[3];
    const float* b_attn = (const float*)d_in[4];
    float* out = (float*)d_out;

    // workspace (26.2 MB): vb | xb | Qt | Kt | ab | wb1 | wb2
    ushort* vb  = (ushort*)d_ws;                   // 2097152 sh (V natural, bf16)
    ushort* xb  = vb + 2097152;                    // 4194304 sh
    ushort* Qt  = xb + 4194304;                    // 2097152 sh
    ushort* Kt  = Qt + 2097152;                    // 2097152 sh
    ushort* ab  = Kt + 2097152;                    // 2097152 sh
    ushort* wb1 = ab + 2097152;                    // 393216 sh
    ushort* wb2 = wb1 + 393216;                    // 131072 sh

    cvt_bf16<<<192, 256, 0, stream>>>(w_qkv, wb1, 49152);
    cvt_bf16<<<64, 256, 0, stream>>>(w_attn, wb2, 16384);
    transpose_cvt<<<dim3(16, 8, BATCH), 256, 0, stream>>>(x, xb, CIN, HW);

    // QKV projection; epilogue writes Qt/Kt (transposed) and vb (V natural)
    gemm_bt<DQKV, CIN, true, 2>
        <<<dim3(8, 6, BATCH), 256, 0, stream>>>(wb1, xb, b_qkv, vb, Qt, Kt);

    attn_kernel<<<dim3(64, BATCH), 512, 0, stream>>>(vb, Qt, Kt, ab);

    gemm_bt<512, 256, false, 0>
        <<<dim3(8, 4, BATCH), 256, 0, stream>>>(wb2, ab, b_attn, out, nullptr, nullptr);
}